// Round 3
// baseline (23.648 us; speedup 1.0000x reference)
//
#include <hip/hip_runtime.h>

// KAConv: out[b,f,h,w] = sum_{c,p} P_fcp(v) / (1 + |Q_fcp(v)|),
//   v = x[b,c,h+i-1,w+j-1] (zero pad), p = i*3+j
// Shapes: x[4,16,64,64], A[16,16,9,6], Bc[16,16,9,4], out[4,16,64,64], f32.
//
// Round 3: coefficients staged in LDS (kills the SGPR-limit s_load chunking
// that serialized rounds 1-2); 2-pixel pair computed as <2 x float> so the
// Horner chains select v_pk_fma_f32; next-c window loads prefetched.

#define BB   4
#define CIN  16
#define COUT 16
#define HH   64
#define WW   64

typedef float v2f __attribute__((ext_vector_type(2)));

static __device__ __forceinline__ v2f sp(float s) { v2f r; r.x = s; r.y = s; return r; }

static __device__ __forceinline__ void loadw(const float* __restrict__ xb, int c,
                                             int r0, int w, float v[4][3]) {
    const float* __restrict__ xc = xb + c * (HH * WW);
    #pragma unroll
    for (int ri = 0; ri < 4; ++ri) {
        const int hh   = r0 - 1 + ri;
        const bool okh = (hh >= 0) & (hh < HH);
        #pragma unroll
        for (int j = 0; j < 3; ++j) {
            const int wj  = w + j - 1;
            const bool ok = okh & (wj >= 0) & (wj < WW);
            v[ri][j] = ok ? xc[hh * WW + wj] : 0.0f;
        }
    }
}

__global__ __launch_bounds__(256) void KAConv_kernel(
    const float* __restrict__ x,    // [B,C,H,W]
    const float* __restrict__ A,    // [F,C,9,6]
    const float* __restrict__ Bc,   // [F,C,9,4]
    float* __restrict__ out)        // [B,F,H,W]
{
    // grid = b(4) x rowtile(8) x f(16) = 512 blocks; block = 256 = 4 waves.
    const int blk   = blockIdx.x;
    const int f     = blk & 15;
    const int rtile = (blk >> 4) & 7;
    const int b     = blk >> 7;

    const int t    = threadIdx.x;
    const int w    = t & 63;
    const int warp = t >> 6;
    const int r0   = (rtile << 3) + (warp << 1);

    // Stage this f's coefficients to LDS once (864 + 576 floats = 5.76 KB).
    __shared__ float sA[CIN * 9 * 6];   // [c][p][6]
    __shared__ float sB[CIN * 9 * 4];   // [c][p][4]
    {
        const float* __restrict__ Af = A  + f * (CIN * 9 * 6);
        const float* __restrict__ Bf = Bc + f * (CIN * 9 * 4);
        for (int i = t; i < CIN * 9 * 6; i += 256) sA[i] = Af[i];
        for (int i = t; i < CIN * 9 * 4; i += 256) sB[i] = Bf[i];
    }
    __syncthreads();

    const float* __restrict__ xb = x + b * (CIN * HH * WW);

    v2f acc = sp(0.0f);

    float vv[4][3], vn[4][3];
    loadw(xb, 0, r0, w, vv);

    #pragma unroll 2
    for (int c = 0; c < CIN; ++c) {
        if (c + 1 < CIN) loadw(xb, c + 1, r0, w, vn);   // prefetch next c

        const float* __restrict__ Ac = sA + c * 54;     // broadcast ds_read
        const float* __restrict__ Bq = sB + c * 36;

        #pragma unroll
        for (int p = 0; p < 9; ++p) {
            const int i = p / 3;
            const int j = p % 3;
            v2f v; v.x = vv[i][j]; v.y = vv[i + 1][j];  // pixel pair

            const float* __restrict__ a  = Ac + p * 6;
            const float* __restrict__ bq = Bq + p * 4;

            // P(v), packed over the pixel pair -> v_pk_fma_f32 chain
            v2f P = sp(a[5]);
            P = P * v + sp(a[4]);
            P = P * v + sp(a[3]);
            P = P * v + sp(a[2]);
            P = P * v + sp(a[1]);
            P = P * v + sp(a[0]);

            // Qs(v) = v*(b1 + v*(b2 + v*(b3 + v*b4)))
            v2f q = sp(bq[3]);
            q = q * v + sp(bq[2]);
            q = q * v + sp(bq[1]);
            q = q * v + sp(bq[0]);
            q = q * v;

            const float d0 = 1.0f + fabsf(q.x);   // v_add_f32 with abs mod
            const float d1 = 1.0f + fabsf(q.y);
            v2f r; r.x = __builtin_amdgcn_rcpf(d0); r.y = __builtin_amdgcn_rcpf(d1);

            acc += P * r;                          // v_pk_fma_f32
        }

        if (c + 1 < CIN) {
            #pragma unroll
            for (int ri = 0; ri < 4; ++ri)
                #pragma unroll
                for (int j = 0; j < 3; ++j)
                    vv[ri][j] = vn[ri][j];
        }
    }

    float* __restrict__ of = out + ((b * COUT + f) * HH) * WW + w;
    of[r0 * WW]       = acc.x;
    of[(r0 + 1) * WW] = acc.y;
}

extern "C" void kernel_launch(void* const* d_in, const int* in_sizes, int n_in,
                              void* d_out, int out_size, void* d_ws, size_t ws_size,
                              hipStream_t stream) {
    const float* x  = (const float*)d_in[0];
    const float* A  = (const float*)d_in[1];
    const float* Bc = (const float*)d_in[2];
    float* out = (float*)d_out;

    const int grid = BB * (HH / 8) * COUT;   // 512 blocks
    KAConv_kernel<<<grid, 256, 0, stream>>>(x, A, Bc, out);
}

// Round 4
// 20.053 us; speedup vs baseline: 1.1793x; 1.1793x over previous
//
#include <hip/hip_runtime.h>

// KAConv: out[b,f,h,w] = sum_{c,p} P_fcp(v) / (1 + |Q_fcp(v)|),
//   v = x[b,c,h+i-1,w+j-1] (zero pad), p = i*3+j
// Shapes: x[4,16,64,64], A[16,16,9,6], Bc[16,16,9,4], out[4,16,64,64], f32.
//
// Round 4: (a) __launch_bounds__(512,4) — match VGPR budget (<=128) to the
// occupancy the grid actually supplies; round 2's VGPR_Count=32 showed the
// compiler serialized the Horner chains chasing unreachable occupancy.
// (b) channel-split teams: block = 2 teams x 256 thr, each team 8 channels
// of an 8-row x 64-col tile (2 px/thread), LDS reduce at the end ->
// 4 waves/SIMD TLP. Coefficients stay on the scalar pipe (s_load): team id
// forced uniform via readfirstlane so addresses stay provably scalar.

#define BB   4
#define CIN  16
#define COUT 16
#define HH   64
#define WW   64

__global__ __launch_bounds__(512, 4) void KAConv_kernel(
    const float* __restrict__ x,    // [B,C,H,W]
    const float* __restrict__ A,    // [F,C,9,6]
    const float* __restrict__ Bc,   // [F,C,9,4]
    float* __restrict__ out)        // [B,F,H,W]
{
    // grid = b(4) x rowtile(8) x f(16) = 512 blocks; block = 512 = 8 waves.
    const int blk   = blockIdx.x;
    const int f     = blk & 15;
    const int rtile = (blk >> 4) & 7;
    const int b     = blk >> 7;

    const int tid  = threadIdx.x;
    // team is wave-uniform (tid>>8 constant across 64-lane waves); force the
    // compiler to see it as scalar so coefficient loads stay s_load.
    const int team = __builtin_amdgcn_readfirstlane(tid >> 8);   // 0 or 1
    const int tp   = tid & 255;
    const int w    = tp & 63;
    const int r0   = (rtile << 3) + ((tp >> 6) << 1);  // rows r0, r0+1
    const int c0   = team << 3;                        // channels c0..c0+7

    const float* __restrict__ xb = x  + (b * CIN + c0) * (HH * WW);
    const float* __restrict__ Af = A  + (f * CIN + c0) * 54;
    const float* __restrict__ Bf = Bc + (f * CIN + c0) * 36;

    __shared__ float sRed[2 * 256];   // team-1 partials (acc0, acc1)

    float acc0 = 0.0f, acc1 = 0.0f;

    for (int c = 0; c < 8; ++c) {
        const float* __restrict__ xc = xb + c * (HH * WW);

        // 4 window rows (r0-1 .. r0+2) x 3 col offsets, zero-padded.
        float vv[4][3];
        #pragma unroll
        for (int ri = 0; ri < 4; ++ri) {
            const int hh   = r0 - 1 + ri;
            const bool okh = (hh >= 0) & (hh < HH);
            #pragma unroll
            for (int j = 0; j < 3; ++j) {
                const int wj  = w + j - 1;
                const bool ok = okh & (wj >= 0) & (wj < WW);
                vv[ri][j] = ok ? xc[hh * WW + wj] : 0.0f;
            }
        }

        const float* __restrict__ Ac = Af + c * 54;   // uniform -> s_load
        const float* __restrict__ Bq = Bf + c * 36;

        #pragma unroll
        for (int p = 0; p < 9; ++p) {
            const int i = p / 3;           // compile-time (full unroll)
            const int j = p % 3;
            const float va = vv[i][j];
            const float vb = vv[i + 1][j];
            const float* __restrict__ a  = Ac + p * 6;
            const float* __restrict__ bq = Bq + p * 4;

            float P0 = a[5], P1 = a[5];
            P0 = fmaf(P0, va, a[4]);  P1 = fmaf(P1, vb, a[4]);
            P0 = fmaf(P0, va, a[3]);  P1 = fmaf(P1, vb, a[3]);
            P0 = fmaf(P0, va, a[2]);  P1 = fmaf(P1, vb, a[2]);
            P0 = fmaf(P0, va, a[1]);  P1 = fmaf(P1, vb, a[1]);
            P0 = fmaf(P0, va, a[0]);  P1 = fmaf(P1, vb, a[0]);

            float q0 = bq[3], q1 = bq[3];
            q0 = fmaf(q0, va, bq[2]); q1 = fmaf(q1, vb, bq[2]);
            q0 = fmaf(q0, va, bq[1]); q1 = fmaf(q1, vb, bq[1]);
            q0 = fmaf(q0, va, bq[0]); q1 = fmaf(q1, vb, bq[0]);
            q0 *= va;                 q1 *= vb;

            const float d0 = 1.0f + fabsf(q0);
            const float d1 = 1.0f + fabsf(q1);
            acc0 = fmaf(P0, __builtin_amdgcn_rcpf(d0), acc0);
            acc1 = fmaf(P1, __builtin_amdgcn_rcpf(d1), acc1);
        }
    }

    // Reduce the two channel-halves: team 1 -> LDS, team 0 adds and stores.
    if (team == 1) {
        sRed[tp]       = acc0;
        sRed[256 + tp] = acc1;
    }
    __syncthreads();
    if (team == 0) {
        acc0 += sRed[tp];
        acc1 += sRed[256 + tp];
        float* __restrict__ of = out + ((b * COUT + f) * HH) * WW + w;
        of[r0 * WW]       = acc0;
        of[(r0 + 1) * WW] = acc1;
    }
}

extern "C" void kernel_launch(void* const* d_in, const int* in_sizes, int n_in,
                              void* d_out, int out_size, void* d_ws, size_t ws_size,
                              hipStream_t stream) {
    const float* x  = (const float*)d_in[0];
    const float* A  = (const float*)d_in[1];
    const float* Bc = (const float*)d_in[2];
    float* out = (float*)d_out;

    const int grid = BB * (HH / 8) * COUT;   // 512 blocks
    KAConv_kernel<<<grid, 512, 0, stream>>>(x, A, Bc, out);
}